// Round 14
// baseline (885.096 us; speedup 1.0000x reference)
//
#include <hip/hip_runtime.h>
#include <hip/hip_bf16.h>

// NewellGRUModel: B=512, S=1024, F=16, H=64.  bf16 in/out (proven r2..r13).
//
// Best-known: r11 (555us) -- VALU, quad K-split, 2 waves/SIMD, VALUBusy 72%,
// ~half of each step still exposed latency. r14 deepens the same lever:
// 8-way K-split, 512-thr blocks (8 waves), 512 blocks -> 4096 waves =
// 4 waves/SIMD. Thread T: unit o = T>>3, k-eighth e = T&7 (k in [8e,8e+8)).
// Gate reduce = shfl_xor 1,2,4 (3 quad/row-perm DPP stages, stay in-group).
// Per-lane: 24 h-FMA + 6 x-FMA, 30 weight VGPRs (true residency under the
// 128 cap of launch_bounds(512,4)). Redundant nonlinearity across split
// lanes is FREE (same wave instruction) -- deeper split doesn't multiply
// transcendental cost. x staged 32 steps/tile, 1 elem/thread. hs reads are
// 2-way bank-aliased (free, m136); xs reads same-address broadcast; h
// writes conflict-free. ONE barrier/step, parity-dbuf hs.

#define KEEP(x) asm volatile("" : "+v"(x))

template<bool BF16>
struct IO {
    static __device__ __forceinline__ float ld(const void* p, int i) {
        if constexpr (BF16) {
            unsigned short u = ((const unsigned short*)p)[i];
            union { unsigned int ui; float f; } c; c.ui = (unsigned int)u << 16;
            return c.f;
        } else {
            return ((const float*)p)[i];
        }
    }
    static __device__ __forceinline__ void st(void* p, int i, float v) {
        if constexpr (BF16) ((__hip_bfloat16*)p)[i] = __float2bfloat16(v);
        else ((float*)p)[i] = v;
    }
};

// mode: 0 = buffers are bf16, 1 = buffers are fp32.
__global__ void detect_dtype_kernel(const void* rkbuf, int* flag) {
    const float* f = (const float*)rkbuf;
    int ok = 0;
    for (int i = 0; i < 64; ++i) {
        float a = fabsf(f[i]);
        ok += (a > 1e-5f && a < 2.0f) ? 1 : 0;
    }
    *flag = (ok >= 48) ? 1 : 0;
}

template<bool BF16>
__global__ __launch_bounds__(512, 4)
void gru_full_kernel(const void* __restrict__ inp, const void* __restrict__ gk,
                     const void* __restrict__ rk,  const void* __restrict__ gb,
                     const void* __restrict__ w1,  const void* __restrict__ b1v,
                     const void* __restrict__ gam, const void* __restrict__ bet,
                     const void* __restrict__ muv, const void* __restrict__ vav,
                     const void* __restrict__ w2,  const void* __restrict__ bb2,
                     const void* __restrict__ Tp,  const int* __restrict__ mode,
                     void* __restrict__ out)
{
    const int want = BF16 ? 0 : 1;
    if (*mode != want) return;   // uniform branch, whole block exits

    const int b     = blockIdx.x;
    const int T     = threadIdx.x;        // 0..511
    const int o     = T >> 3;             // this thread's output unit (0..63)
    const int e     = T & 7;              // k-eighth
    const int kbase = 8 * e;

    __shared__ __align__(16) float xs[2][32][16];  // x tile: 32 steps x 16 ch
    __shared__ __align__(16) float hs[2][64];      // h, dbuf by step parity
    __shared__ __align__(16) float sred[64];       // epilogue exchange

    using io = IO<BF16>;

    // ---- recurrent weights: 8 k-rows for this thread's k-eighth ----
    float wz[8], wr[8], wh[8];
#pragma unroll
    for (int i = 0; i < 8; ++i) {
        const int row = kbase + i;
        wz[i] = io::ld(rk, row*192 + o);
        wr[i] = io::ld(rk, row*192 + 64 + o);
        wh[i] = io::ld(rk, row*192 + 128 + o);
        KEEP(wz[i]); KEEP(wr[i]); KEEP(wh[i]);
    }
    // ---- x-proj weights: 2 channels per k-eighth (ch15 weight = 0 pad) ----
    float kz[2], kr[2], khw[2];
#pragma unroll
    for (int c = 0; c < 2; ++c) {
        const int ch = 2*e + c;
        const bool v = (ch < 15);
        kz[c]  = v ? io::ld(gk, ch*192 + o)       : 0.0f;
        kr[c]  = v ? io::ld(gk, ch*192 + 64 + o)  : 0.0f;
        khw[c] = v ? io::ld(gk, ch*192 + 128 + o) : 0.0f;
        KEEP(kz[c]); KEEP(kr[c]); KEEP(khw[c]);
    }
    // biases only in e==0 partials (summed once by the reduce)
    float bz  = e ? 0.0f : (io::ld(gb, o)      + io::ld(gb, 192 + o));
    float br  = e ? 0.0f : (io::ld(gb, 64 + o) + io::ld(gb, 192 + 64 + o));
    float bah = e ? 0.0f : io::ld(gb, 192 + 128 + o);   // b_r[h]
    float bax = e ? 0.0f : io::ld(gb, 128 + o);         // b_i[h]
    const float hsel = (e == 7) ? 1.0f : 0.0f;          // ch15 -> dsum

    if (T < 64) hs[0][T] = 0.0f;   // h0 = 0
    __syncthreads();

    const int xbase = b * 16384;   // elements
    float xreg = io::ld(inp, xbase + T);   // tile 0: 1 elem/thread (32 steps)

    float h = 0.0f, dsum = 0.0f;

#pragma unroll 1
    for (int t = 0; t < 32; ++t) {
        xs[t & 1][T >> 4][T & 15] = xreg;
        __syncthreads();               // staging visible (1 extra / 32 steps)
        if (t < 31) xreg = io::ld(inp, xbase + (t + 1) * 512 + T);

#pragma unroll 1
        for (int s2 = 0; s2 < 32; ++s2) {
            const int s = t * 32 + s2;

            // x: this thread's 2 channels; h: this thread's 8 k-values
            const float2 xv = *(const float2*)&xs[t & 1][s2][2*e];
            const float4* hp = (const float4*)&hs[s & 1][kbase];
            float4 p0 = hp[0], p1 = hp[1];
            asm volatile("" ::: "memory");

            // ---- x part (6 FMA) ----
            float az = bz, ar = br, ax = bax;
            az = fmaf(xv.x, kz[0], az); ar = fmaf(xv.x, kr[0], ar); ax = fmaf(xv.x, khw[0], ax);
            az = fmaf(xv.y, kz[1], az); ar = fmaf(xv.y, kr[1], ar); ax = fmaf(xv.y, khw[1], ax);
            dsum = fmaf(hsel, xv.y, dsum);   // ch15 (e==7 threads only)

            // ---- h part (24 FMA, 2 chains per gate) ----
            float az1 = 0.f, ar1 = 0.f, ah0 = 0.f, ah1 = 0.f;
            az  = fmaf(p0.x, wz[0], az);
            ar  = fmaf(p0.x, wr[0], ar);
            ah0 = fmaf(p0.x, wh[0], ah0);
            az  = fmaf(p0.y, wz[1], az);
            ar  = fmaf(p0.y, wr[1], ar);
            ah0 = fmaf(p0.y, wh[1], ah0);
            az  = fmaf(p0.z, wz[2], az);
            ar  = fmaf(p0.z, wr[2], ar);
            ah0 = fmaf(p0.z, wh[2], ah0);
            az  = fmaf(p0.w, wz[3], az);
            ar  = fmaf(p0.w, wr[3], ar);
            ah0 = fmaf(p0.w, wh[3], ah0);
            az1 = fmaf(p1.x, wz[4], az1);
            ar1 = fmaf(p1.x, wr[4], ar1);
            ah1 = fmaf(p1.x, wh[4], ah1);
            az1 = fmaf(p1.y, wz[5], az1);
            ar1 = fmaf(p1.y, wr[5], ar1);
            ah1 = fmaf(p1.y, wh[5], ah1);
            az1 = fmaf(p1.z, wz[6], az1);
            ar1 = fmaf(p1.z, wr[6], ar1);
            ah1 = fmaf(p1.z, wh[6], ah1);
            az1 = fmaf(p1.w, wz[7], az1);
            ar1 = fmaf(p1.w, wr[7], ar1);
            ah1 = fmaf(p1.w, wh[7], ah1);
            az += az1;
            ar += ar1;
            float ah = bah + ah0 + ah1;

            // ---- 8-way reduce: xor 1,2,4 (row-perm DPP, stays in group) ----
            az += __shfl_xor(az, 1, 64);  az += __shfl_xor(az, 2, 64);  az += __shfl_xor(az, 4, 64);
            ar += __shfl_xor(ar, 1, 64);  ar += __shfl_xor(ar, 2, 64);  ar += __shfl_xor(ar, 4, 64);
            ah += __shfl_xor(ah, 1, 64);  ah += __shfl_xor(ah, 2, 64);  ah += __shfl_xor(ah, 4, 64);
            ax += __shfl_xor(ax, 1, 64);  ax += __shfl_xor(ax, 2, 64);  ax += __shfl_xor(ax, 4, 64);

            const float z   = __builtin_amdgcn_rcpf(1.0f + __expf(-az));
            const float r   = __builtin_amdgcn_rcpf(1.0f + __expf(-ar));
            const float pre = fmaf(r, ah, ax);
            const float e2  = __expf(2.0f * pre);
            const float th  = 1.0f - 2.0f * __builtin_amdgcn_rcpf(e2 + 1.0f);
            h = fmaf(z, h - th, th);   // z*h + (1-z)*tanh (all 8 group lanes)

            if (e == 0) hs[(s + 1) & 1][o] = h;   // publish to NEXT buffer
            __syncthreads();           // the ONE barrier per step
        }
    }

    // ---- epilogue: delta effect + dense head ----
    const float T0 = io::ld(Tp, 0);
    if (e == 7) sred[o] = fmaf(T0 * (1.0f / 1024.0f), dsum, h);  // e==7 holds dsum
    __syncthreads();

    if (T < 64) {   // one wave does the head
        const int j = T;   // 0..63
        float acc = io::ld(b1v, j);
#pragma unroll
        for (int k = 0; k < 64; ++k)
            acc = fmaf(sred[k], io::ld(w1, k*64 + j), acc);
        acc = fmaxf(acc, 0.0f);                                  // ReLU
        const float inv = rsqrtf(io::ld(vav, j) + 0.001f);       // BN_EPS
        acc = fmaf((acc - io::ld(muv, j)) * inv, io::ld(gam, j), io::ld(bet, j));

        float v = acc * io::ld(w2, j);
#pragma unroll
        for (int off = 32; off > 0; off >>= 1)
            v += __shfl_down(v, off);
        if (j == 0) io::st(out, b, v + io::ld(bb2, 0));
    }
}

extern "C" void kernel_launch(void* const* d_in, const int* in_sizes, int n_in,
                              void* d_out, int out_size, void* d_ws, size_t ws_size,
                              hipStream_t stream)
{
    const void* inp = d_in[0];   // (512,1024,16)
    const void* gk  = d_in[1];   // (15,192)
    const void* rk  = d_in[2];   // (64,192)
    const void* gb  = d_in[3];   // (2,192)
    const void* w1  = d_in[4];   // (64,64)
    const void* b1v = d_in[5];   // (64,)
    const void* gam = d_in[6];
    const void* bet = d_in[7];
    const void* muv = d_in[8];
    const void* vav = d_in[9];
    const void* w2  = d_in[10];  // (64,1)
    const void* bb2 = d_in[11];  // (1,)
    const void* Tp  = d_in[12];  // (1,)

    int* flag = (int*)d_ws;
    detect_dtype_kernel<<<dim3(1), dim3(1), 0, stream>>>(rk, flag);
    gru_full_kernel<true ><<<dim3(512), dim3(512), 0, stream>>>(
        inp, gk, rk, gb, w1, b1v, gam, bet, muv, vav, w2, bb2, Tp, flag, d_out);
    gru_full_kernel<false><<<dim3(512), dim3(512), 0, stream>>>(
        inp, gk, rk, gb, w1, b1v, gam, bet, muv, vav, w2, bb2, Tp, flag, d_out);
}